// Round 11
// baseline (262.407 us; speedup 1.0000x reference)
//
#include <hip/hip_runtime.h>
#include <math.h>

constexpr int NN = 4096, DD = 64, TT = 60, HH = 128, GG = 512, KK = 192;

typedef _Float16 h8 __attribute__((ext_vector_type(8)));
typedef float f4 __attribute__((ext_vector_type(4)));

// ws layout (float offsets)
constexpr size_t XNT = 0;                                  // half [T][N][D] RAW x fp16; REUSED later as swizzled hbn16
constexpr size_t WFRG = (size_t)TT * NN * DD / 2;          // half [w][g][ks][lane][8] = 98304 halves (UNfolded)
constexpr size_t BSUM = WFRG + 98304 / 2;                  // [512] f32 folded bias
constexpr size_t SC1 = BSUM + GG;                          // [64] (scratch)
constexpr size_t SH1 = SC1 + DD;                           // [64]
constexpr size_t HID = SH1 + DD;                           // [N][H] f32; ALSO h@29 hand-off between k_lstmA/B
constexpr size_t HBN = HID + (size_t)NN * HH;              // [N][H]; ALSO c@29 hand-off (k_hbn writes it later)
constexpr size_t SC2 = HBN + (size_t)NN * HH;              // [128] (unused now)
constexpr size_t SH2 = SC2 + HH;
constexpr size_t U1O = SH2 + HH;
constexpr size_t U2O = U1O + HH;
constexpr size_t CCO = U2O + HH;                           // [4]: c1, c2, s1max(encoded uint)
constexpr size_t S1O = CCO + 4;                            // [N]
constexpr size_t S2O = S1O + NN;
constexpr size_t H2O = S2O + NN;                           // BN1 per-block partials [1024][128] (512 KB), else unused
constexpr size_t SSUM = H2O + (size_t)NN * HH;             // [132:260) bn2 sum, [260:388) bn2 sumsq (atomic accum)
constexpr size_t SC16 = SSUM + 392;                        // fp16[64] sc1 (32 floats)

// Fast activations: v_rcp_f32 (1 ulp) instead of correctly-rounded fp32 divide.
__device__ __forceinline__ float fastrcp_(float x) { return __builtin_amdgcn_rcpf(x); }
__device__ __forceinline__ float sigmoidf_(float x) { return fastrcp_(1.f + __expf(-x)); }
__device__ __forceinline__ float tanhfast_(float x) { return 1.f - 2.f * fastrcp_(__expf(2.f * x) + 1.f); }
__device__ __forceinline__ float leakyf_(float z) { return fmaxf(z, 0.01f * z); }

__device__ __forceinline__ unsigned fenc_(float f) {
    unsigned b = __float_as_uint(f);
    return (b & 0x80000000u) ? ~b : (b | 0x80000000u);
}
__device__ __forceinline__ float fdec_(unsigned u) {
    return (u & 0x80000000u) ? __uint_as_float(u & 0x7fffffffu) : __uint_as_float(~u);
}

constexpr int TSTR = 264;  // halves per t-row in staging LDS

// ---- k_pre: blocks [0,1024) BN1 stats + fp16 transpose (partials to distinct
//      slots, NO done-counter); [1024,1408) weight swizzle; 1408 u/v/c prep. ----
__global__ __launch_bounds__(256) void k_pre(const float* __restrict__ x,
                                             const float* __restrict__ Wih,
                                             const float* __restrict__ Whh,
                                             const float* __restrict__ Wt,
                                             const float* __restrict__ bt,
                                             const float* __restrict__ a,
                                             float* __restrict__ ws) {
    int b = blockIdx.x;
    int tid = threadIdx.x;
    if (b >= 1024) {
        if (b == 1408) {
            int k = tid;
            if (k < HH) {
                float u1 = 0.f, u2 = 0.f;
                for (int j = 0; j < HH; j++) {
                    float w = Wt[j * HH + k];
                    u1 = fmaf(w, a[j], u1);
                    u2 = fmaf(w, a[HH + j], u2);
                }
                ws[U1O + k] = u1;
                ws[U2O + k] = u2;
                if (k == 0) {
                    float c1 = 0.f, c2 = 0.f;
                    for (int j = 0; j < HH; j++) {
                        c1 = fmaf(bt[j], a[j], c1);
                        c2 = fmaf(bt[j], a[HH + j], c2);
                    }
                    ws[CCO] = c1;
                    ws[CCO + 1] = c2;
                    ((unsigned*)ws)[CCO + 2] = fenc_(-1e30f);
                }
            }
            return;
        }
        // parallel weight swizzle (UNfolded): frag (w,g,ks): W[k][col],
        // col=g*128+w*16+(lane&15), k=ks*32+(lane>>4)*8+j
        int o = (b - 1024) * 256 + tid;
        _Float16* wf = (_Float16*)(ws + WFRG);
        int j = o & 7;
        int lane = (o >> 3) & 63;
        int rest = o >> 9;
        int ks = rest % 6;
        int gw = rest / 6;
        int g = gw & 3, w = gw >> 2;
        int col = g * 128 + w * 16 + (lane & 15);
        int k = ks * 32 + (lane >> 4) * 8 + j;
        float v = (k < DD) ? Wih[col * DD + k] : Whh[col * HH + (k - DD)];
        wf[o] = (_Float16)v;
        return;
    }
    // ---- xstats: rows n0..n0+3; coalesced reads; LDS [t][k] staging; b64 copy-out ----
    __shared__ _Float16 stg[TT * TSTR];
    __shared__ float rs[256], rss[256];
    const float4* xb = (const float4*)(x + (size_t)b * 15360);
#pragma unroll
    for (int q = 0; q < 15; q++) {
        int f = q * 256 + tid;
        float4 v = xb[f];
        int k = f / 15, t0 = (f - k * 15) * 4;
        stg[(t0 + 0) * TSTR + k] = (_Float16)v.x;
        stg[(t0 + 1) * TSTR + k] = (_Float16)v.y;
        stg[(t0 + 2) * TSTR + k] = (_Float16)v.z;
        stg[(t0 + 3) * TSTR + k] = (_Float16)v.w;
    }
    __syncthreads();
    {
        int k = tid;
        float s = 0.f, ss = 0.f;
#pragma unroll
        for (int t = 0; t < TT; t++) {
            float v = (float)stg[t * TSTR + k];
            s += v;
            ss = fmaf(v, v, ss);
        }
        rs[tid] = s; rss[tid] = ss;
    }
    __syncthreads();
    if (tid < 64) {
        float ts = rs[tid] + rs[64 + tid] + rs[128 + tid] + rs[192 + tid];
        float tss = rss[tid] + rss[64 + tid] + rss[128 + tid] + rss[192 + tid];
        float* pp = ws + H2O + (size_t)b * 128;
        pp[tid] = ts;
        pp[64 + tid] = tss;
    }
    // copy-out: xnT[t][n0..n0+3][0..63]
    _Float16* outp = (_Float16*)ws;
    int n0 = b * 4;
    for (int p = tid; p < 3840; p += 256) {
        int t = p >> 6, i = p & 63;
        *(uint2*)(outp + ((size_t)t * NN + n0) * DD + i * 4) =
            *(const uint2*)(stg + t * TSTR + i * 4);
    }
}

// ---- k_fin1: single block, 1024 threads. Zero BN2 accum; reduce 1024x128 BN1
//      partials; sc/sh; fp16 sc1; bias fold. ----
__global__ __launch_bounds__(1024) void k_fin1(const float* __restrict__ g1,
                                               const float* __restrict__ b1,
                                               const float* __restrict__ Wih,
                                               const float* __restrict__ bih,
                                               const float* __restrict__ bhh,
                                               float* __restrict__ ws) {
    __shared__ float p2[32][128];
    __shared__ float scs[64], shs[64];
    int tid = threadIdx.x;
    if (tid < 392) ws[SSUM + tid] = 0.f;
    {
        int rb = tid >> 5;
        int c0 = (tid & 31) * 4;
        const float* pb = ws + H2O + (size_t)rb * 32 * 128;
        float4 s4 = {0.f, 0.f, 0.f, 0.f};
        for (int bb = 0; bb < 32; bb++) {
            float4 v = *(const float4*)(pb + (size_t)bb * 128 + c0);
            s4.x += v.x; s4.y += v.y; s4.z += v.z; s4.w += v.w;
        }
        p2[rb][c0 + 0] = s4.x;
        p2[rb][c0 + 1] = s4.y;
        p2[rb][c0 + 2] = s4.z;
        p2[rb][c0 + 3] = s4.w;
    }
    __syncthreads();
    if (tid < 64) {
        float s_ = 0.f, ss_ = 0.f;
#pragma unroll
        for (int g = 0; g < 32; g++) {
            s_ += p2[g][tid];
            ss_ += p2[g][64 + tid];
        }
        float cnt = (float)(NN * TT);
        float m = s_ / cnt;
        float var = ss_ / cnt - m * m;
        float sc = g1[tid] * rsqrtf(var + 1e-5f);
        scs[tid] = sc;
        shs[tid] = b1[tid] - m * sc;
        ((_Float16*)(ws + SC16))[tid] = (_Float16)sc;
    }
    __syncthreads();
    if (tid < GG) {
        int c = tid;
        float bsum = bih[c] + bhh[c];
        const float4* wr = (const float4*)(Wih + c * 64);
#pragma unroll
        for (int q = 0; q < 16; q++) {
            float4 wv = wr[q];
            bsum = fmaf(wv.x, shs[q * 4 + 0], fmaf(wv.y, shs[q * 4 + 1],
                   fmaf(wv.z, shs[q * 4 + 2], fmaf(wv.w, shs[q * 4 + 3], bsum))));
        }
        ws[BSUM + c] = bsum;
    }
}

// ---- LSTM split in half for top-5 visibility of the non-LSTM kernels
//      (diagnostic: drops the rocprof top-5 cutoff from ~79 to ~40 µs).
//      State hand-off h@29 (f32, via HID) + c@29 (f32, via HBN — both regions
//      dead at that point). h re-enters as fp16 exactly as the hlds path did
//      -> bit-identical numerics. ----
__global__ __launch_bounds__(512, 1) void k_lstmA(float* __restrict__ ws) {
    int tid = threadIdx.x;
    int w = tid >> 6, lane = tid & 63;
    int quad = lane >> 4, m = lane & 15;
    int r0 = blockIdx.x * 16;
    __shared__ _Float16 hlds[2][16][136];
    const _Float16* wf = (const _Float16*)(ws + WFRG);

    h8 bw[4][6];
#pragma unroll
    for (int g = 0; g < 4; g++)
#pragma unroll
        for (int ks = 0; ks < 6; ks++)
            bw[g][ks] = *(const h8*)(wf + ((((w * 4 + g) * 6 + ks) * 64 + lane) * 8));

    f4 xbias[4];
#pragma unroll
    for (int g = 0; g < 4; g++) {
        float bv = ws[BSUM + g * 128 + w * 16 + m];
        xbias[g] = (f4){bv, bv, bv, bv};
    }

    const _Float16* sc16 = (const _Float16*)(ws + SC16);
    {
        h8 scv0 = *(const h8*)(sc16 + quad * 8);
        h8 scv1 = *(const h8*)(sc16 + 32 + quad * 8);
#pragma unroll
        for (int g = 0; g < 4; g++) { bw[g][0] *= scv0; bw[g][1] *= scv1; }
    }

    for (int p = tid; p < 2 * 16 * 136; p += 512) ((_Float16*)hlds)[p] = (_Float16)0.f;

    f4 cst = {};
    float hv[4];
    const _Float16* xb = (const _Float16*)ws + (size_t)(r0 + m) * DD + quad * 8;
    int col = w * 16 + m;
    __syncthreads();

    h8 ax0 = *(const h8*)xb;
    h8 ax1 = *(const h8*)(xb + 32);
    f4 xA[4], xB[4];
#pragma unroll
    for (int g = 0; g < 4; g++) xA[g] = __builtin_amdgcn_mfma_f32_16x16x32_f16(ax0, bw[g][0], xbias[g], 0, 0, 0);
#pragma unroll
    for (int g = 0; g < 4; g++) xA[g] = __builtin_amdgcn_mfma_f32_16x16x32_f16(ax1, bw[g][1], xA[g], 0, 0, 0);

    for (int t = 0; t < 30; t += 2) {
        // even step: consume xA, write h to hlds[0], build xB for t+1
        {
            h8 ah[4];
            const _Float16* hb = &hlds[1][m][quad * 8];
#pragma unroll
            for (int ks = 0; ks < 4; ks++) ah[ks] = *(const h8*)(hb + ks * 32);
            const _Float16* xp = xb + (size_t)(t + 1) * NN * DD;
            h8 nx0 = *(const h8*)xp;
            h8 nx1 = *(const h8*)(xp + 32);
#pragma unroll
            for (int ks = 0; ks < 4; ks++)
#pragma unroll
                for (int g = 0; g < 4; g++)
                    xA[g] = __builtin_amdgcn_mfma_f32_16x16x32_f16(ah[ks], bw[g][ks + 2], xA[g], 0, 0, 0);
#pragma unroll
            for (int r = 0; r < 4; r++) {
                float ig = sigmoidf_(xA[0][r]);
                float fg = sigmoidf_(xA[1][r]);
                float gg = tanhfast_(xA[2][r]);
                float og = sigmoidf_(xA[3][r]);
                float c = fmaf(fg, cst[r], ig * gg);
                cst[r] = c;
                hv[r] = og * tanhfast_(c);
            }
            _Float16* wbuf = &hlds[0][0][0];
#pragma unroll
            for (int r = 0; r < 4; r++) wbuf[(quad * 4 + r) * 136 + col] = (_Float16)hv[r];
#pragma unroll
            for (int g = 0; g < 4; g++) xB[g] = __builtin_amdgcn_mfma_f32_16x16x32_f16(nx0, bw[g][0], xbias[g], 0, 0, 0);
#pragma unroll
            for (int g = 0; g < 4; g++) xB[g] = __builtin_amdgcn_mfma_f32_16x16x32_f16(nx1, bw[g][1], xB[g], 0, 0, 0);
            asm volatile("s_waitcnt lgkmcnt(0)\n\ts_barrier" ::: "memory");
        }
        // odd step: consume xB, write h to hlds[1], build xA for t+2 (t+2<=30 valid)
        {
            h8 ah[4];
            const _Float16* hb = &hlds[0][m][quad * 8];
#pragma unroll
            for (int ks = 0; ks < 4; ks++) ah[ks] = *(const h8*)(hb + ks * 32);
            const _Float16* xp = xb + (size_t)(t + 2) * NN * DD;
            h8 nx0 = *(const h8*)xp;
            h8 nx1 = *(const h8*)(xp + 32);
#pragma unroll
            for (int ks = 0; ks < 4; ks++)
#pragma unroll
                for (int g = 0; g < 4; g++)
                    xB[g] = __builtin_amdgcn_mfma_f32_16x16x32_f16(ah[ks], bw[g][ks + 2], xB[g], 0, 0, 0);
#pragma unroll
            for (int r = 0; r < 4; r++) {
                float ig = sigmoidf_(xB[0][r]);
                float fg = sigmoidf_(xB[1][r]);
                float gg = tanhfast_(xB[2][r]);
                float og = sigmoidf_(xB[3][r]);
                float c = fmaf(fg, cst[r], ig * gg);
                cst[r] = c;
                hv[r] = og * tanhfast_(c);
            }
            _Float16* wbuf = &hlds[1][0][0];
#pragma unroll
            for (int r = 0; r < 4; r++) wbuf[(quad * 4 + r) * 136 + col] = (_Float16)hv[r];
#pragma unroll
            for (int g = 0; g < 4; g++) xA[g] = __builtin_amdgcn_mfma_f32_16x16x32_f16(nx0, bw[g][0], xbias[g], 0, 0, 0);
#pragma unroll
            for (int g = 0; g < 4; g++) xA[g] = __builtin_amdgcn_mfma_f32_16x16x32_f16(nx1, bw[g][1], xA[g], 0, 0, 0);
            asm volatile("s_waitcnt lgkmcnt(0)\n\ts_barrier" ::: "memory");
        }
    }
    // state out: h@29 (f32 -> HID), c@29 (f32 -> HBN)
#pragma unroll
    for (int r = 0; r < 4; r++) {
        ws[HID + (size_t)(r0 + quad * 4 + r) * HH + col] = hv[r];
        ws[HBN + (size_t)(r0 + quad * 4 + r) * HH + col] = cst[r];
    }
}

__global__ __launch_bounds__(512, 1) void k_lstmB(float* __restrict__ ws) {
    int tid = threadIdx.x;
    int w = tid >> 6, lane = tid & 63;
    int quad = lane >> 4, m = lane & 15;
    int r0 = blockIdx.x * 16;
    __shared__ _Float16 hlds[2][16][136];
    const _Float16* wf = (const _Float16*)(ws + WFRG);

    h8 bw[4][6];
#pragma unroll
    for (int g = 0; g < 4; g++)
#pragma unroll
        for (int ks = 0; ks < 6; ks++)
            bw[g][ks] = *(const h8*)(wf + ((((w * 4 + g) * 6 + ks) * 64 + lane) * 8));

    f4 xbias[4];
#pragma unroll
    for (int g = 0; g < 4; g++) {
        float bv = ws[BSUM + g * 128 + w * 16 + m];
        xbias[g] = (f4){bv, bv, bv, bv};
    }

    const _Float16* sc16 = (const _Float16*)(ws + SC16);
    {
        h8 scv0 = *(const h8*)(sc16 + quad * 8);
        h8 scv1 = *(const h8*)(sc16 + 32 + quad * 8);
#pragma unroll
        for (int g = 0; g < 4; g++) { bw[g][0] *= scv0; bw[g][1] *= scv1; }
    }

    // state in: h@29 -> hlds[1] (as fp16, same as original hlds path), c@29 -> cst
    f4 cst;
    float hv[4];
    int col = w * 16 + m;
    {
        _Float16* wbuf1 = &hlds[1][0][0];
#pragma unroll
        for (int r = 0; r < 4; r++) {
            int row = quad * 4 + r;
            float hval = ws[HID + (size_t)(r0 + row) * HH + col];
            wbuf1[row * 136 + col] = (_Float16)hval;
            cst[r] = ws[HBN + (size_t)(r0 + row) * HH + col];
        }
    }
    const _Float16* xb = (const _Float16*)ws + (size_t)(r0 + m) * DD + quad * 8;
    __syncthreads();

    // x prologue @ t=30
    {
        const _Float16* xp30 = xb + (size_t)30 * NN * DD;
        h8 ax0 = *(const h8*)xp30;
        h8 ax1 = *(const h8*)(xp30 + 32);
        // fallthrough into xA init below
        f4 tmp0[4];
#pragma unroll
        for (int g = 0; g < 4; g++) tmp0[g] = __builtin_amdgcn_mfma_f32_16x16x32_f16(ax0, bw[g][0], xbias[g], 0, 0, 0);
#pragma unroll
        for (int g = 0; g < 4; g++) tmp0[g] = __builtin_amdgcn_mfma_f32_16x16x32_f16(ax1, bw[g][1], tmp0[g], 0, 0, 0);
        // store into xA
        {
            f4 xA[4], xB[4];
#pragma unroll
            for (int g = 0; g < 4; g++) xA[g] = tmp0[g];

            for (int t = 30; t < TT; t += 2) {
                // even step: consume xA, write h to hlds[0], build xB for t+1
                {
                    h8 ah[4];
                    const _Float16* hb = &hlds[1][m][quad * 8];
#pragma unroll
                    for (int ks = 0; ks < 4; ks++) ah[ks] = *(const h8*)(hb + ks * 32);
                    const _Float16* xp = xb + (size_t)(t + 1) * NN * DD;
                    h8 nx0 = *(const h8*)xp;
                    h8 nx1 = *(const h8*)(xp + 32);
#pragma unroll
                    for (int ks = 0; ks < 4; ks++)
#pragma unroll
                        for (int g = 0; g < 4; g++)
                            xA[g] = __builtin_amdgcn_mfma_f32_16x16x32_f16(ah[ks], bw[g][ks + 2], xA[g], 0, 0, 0);
#pragma unroll
                    for (int r = 0; r < 4; r++) {
                        float ig = sigmoidf_(xA[0][r]);
                        float fg = sigmoidf_(xA[1][r]);
                        float gg = tanhfast_(xA[2][r]);
                        float og = sigmoidf_(xA[3][r]);
                        float c = fmaf(fg, cst[r], ig * gg);
                        cst[r] = c;
                        hv[r] = og * tanhfast_(c);
                    }
                    _Float16* wbuf = &hlds[0][0][0];
#pragma unroll
                    for (int r = 0; r < 4; r++) wbuf[(quad * 4 + r) * 136 + col] = (_Float16)hv[r];
#pragma unroll
                    for (int g = 0; g < 4; g++) xB[g] = __builtin_amdgcn_mfma_f32_16x16x32_f16(nx0, bw[g][0], xbias[g], 0, 0, 0);
#pragma unroll
                    for (int g = 0; g < 4; g++) xB[g] = __builtin_amdgcn_mfma_f32_16x16x32_f16(nx1, bw[g][1], xB[g], 0, 0, 0);
                    asm volatile("s_waitcnt lgkmcnt(0)\n\ts_barrier" ::: "memory");
                }
                // odd step: consume xB, write h to hlds[1], build xA for t+2
                {
                    h8 ah[4];
                    const _Float16* hb = &hlds[0][m][quad * 8];
#pragma unroll
                    for (int ks = 0; ks < 4; ks++) ah[ks] = *(const h8*)(hb + ks * 32);
                    h8 nx0 = {}, nx1 = {};
                    if (t + 2 < TT) {
                        const _Float16* xp = xb + (size_t)(t + 2) * NN * DD;
                        nx0 = *(const h8*)xp;
                        nx1 = *(const h8*)(xp + 32);
                    }
#pragma unroll
                    for (int ks = 0; ks < 4; ks++)
#pragma unroll
                        for (int g = 0; g < 4; g++)
                            xB[g] = __builtin_amdgcn_mfma_f32_16x16x32_f16(ah[ks], bw[g][ks + 2], xB[g], 0, 0, 0);
#pragma unroll
                    for (int r = 0; r < 4; r++) {
                        float ig = sigmoidf_(xB[0][r]);
                        float fg = sigmoidf_(xB[1][r]);
                        float gg = tanhfast_(xB[2][r]);
                        float og = sigmoidf_(xB[3][r]);
                        float c = fmaf(fg, cst[r], ig * gg);
                        cst[r] = c;
                        hv[r] = og * tanhfast_(c);
                    }
                    _Float16* wbuf = &hlds[1][0][0];
#pragma unroll
                    for (int r = 0; r < 4; r++) wbuf[(quad * 4 + r) * 136 + col] = (_Float16)hv[r];
#pragma unroll
                    for (int g = 0; g < 4; g++) xA[g] = __builtin_amdgcn_mfma_f32_16x16x32_f16(nx0, bw[g][0], xbias[g], 0, 0, 0);
#pragma unroll
                    for (int g = 0; g < 4; g++) xA[g] = __builtin_amdgcn_mfma_f32_16x16x32_f16(nx1, bw[g][1], xA[g], 0, 0, 0);
                    asm volatile("s_waitcnt lgkmcnt(0)\n\ts_barrier" ::: "memory");
                }
            }
        }
    }
#pragma unroll
    for (int r = 0; r < 4; r++)
        ws[HID + (size_t)(r0 + quad * 4 + r) * HH + col] = hv[r];

    // BN2 partial sums (wave-local reduce; 1 atomic/col to 256 distinct addrs)
    float s = hv[0] + hv[1] + hv[2] + hv[3];
    float ss = fmaf(hv[0], hv[0], fmaf(hv[1], hv[1], fmaf(hv[2], hv[2], hv[3] * hv[3])));
    s += __shfl_xor(s, 16, 64); s += __shfl_xor(s, 32, 64);
    ss += __shfl_xor(ss, 16, 64); ss += __shfl_xor(ss, 32, 64);
    if (quad == 0) {
        atomicAdd(&ws[SSUM + 132 + col], s);
        atomicAdd(&ws[SSUM + 260 + col], ss);
    }
}

// ---- apply BN2 (sc/sh computed in-block from SSUM — no k_fin2 dispatch):
//      s1, s2, fp32 hbn, LDS-staged coalesced swizzled fp16 hbn, s1max ----
__global__ void k_hbn(const float* __restrict__ g2,
                      const float* __restrict__ b2,
                      float* __restrict__ ws) {
    __shared__ float sc[HH], sh[HH], u1s[HH], u2s[HH];
    __shared__ _Float16 swz[4096];
    int tid = threadIdx.x;
    if (tid < HH) {
        float mm = ws[SSUM + 132 + tid] * (1.f / (float)NN);
        float var = ws[SSUM + 260 + tid] * (1.f / (float)NN) - mm * mm;
        float scv = g2[tid] * rsqrtf(var + 1e-5f);
        sc[tid] = scv;
        sh[tid] = b2[tid] - mm * scv;
        u1s[tid] = ws[U1O + tid]; u2s[tid] = ws[U2O + tid];
    }
    __syncthreads();
    int r = tid >> 3, l = tid & 7;
    int n = blockIdx.x * 32 + r;
    const float* hr = ws + HID + (size_t)n * HH;
    float* hb = ws + HBN + (size_t)n * HH;
    int lanehi = (r >> 3);
    int jj = r & 7;
    float d1 = 0.f, d2 = 0.f;
    int k0 = l * 16;
#pragma unroll
    for (int q4 = 0; q4 < 4; q4++) {
        float4 hv4 = *(const float4*)&hr[k0 + q4 * 4];
        float4 o;
#pragma unroll
        for (int c = 0; c < 4; c++) {
            int kk = k0 + q4 * 4 + c;
            float v = fmaf(((const float*)&hv4)[c], sc[kk], sh[kk]);
            ((float*)&o)[c] = v;
            swz[l * 512 + (lanehi * 16 + (kk & 15)) * 8 + jj] = (_Float16)v;
            d1 = fmaf(v, u1s[kk], d1);
            d2 = fmaf(v, u2s[kk], d2);
        }
        *(float4*)&hb[k0 + q4 * 4] = o;
    }
#pragma unroll
    for (int o = 1; o < 8; o <<= 1) { d1 += __shfl_xor(d1, o, 64); d2 += __shfl_xor(d2, o, 64); }
    if (l == 0) {
        float s1 = d1 + ws[CCO];
        ws[S1O + n] = s1;
        ws[S2O + n] = d2 + ws[CCO + 1];
        atomicMax((unsigned*)ws + CCO + 2, fenc_(s1));
    }
    __syncthreads();
    _Float16* dst = (_Float16*)ws + (size_t)blockIdx.x * 4096;
    for (int p = tid; p < 512; p += 256)
        *(h8*)(dst + p * 8) = *(const h8*)(swz + p * 8);
}

// ---- attention + fc fused; waves split the j-range (exp dedup) ----
__global__ __launch_bounds__(512, 1) void k_attfc(const float* __restrict__ Wfc,
                                                  const float* __restrict__ bfc,
                                                  const float* __restrict__ Wout,
                                                  const float* __restrict__ bout,
                                                  float* __restrict__ ws,
                                                  float* __restrict__ out) {
    __shared__ float ls1[NN];
    __shared__ float red[4][16][132];
    __shared__ float psr[4][16];
    __shared__ float h2s[16][132];
    int tid = threadIdx.x;
    int w = tid >> 6, lane = tid & 63;
    int quad = lane >> 4, m = lane & 15;
    int whalf = w >> 2, jsplit = w & 3;
    int n0 = blockIdx.x * 16;
    for (int i = tid; i < NN; i += 512) ls1[i] = ws[S1O + i];
    __syncthreads();
    float s1max = fdec_(((unsigned*)ws)[CCO + 2]);
    float s2n = ws[S2O + n0 + m];
    float mi = leakyf_(s2n + s1max);
    const _Float16* hbsw = (const _Float16*)ws;
    f4 acc[4] = {};
    float psum = 0.f;
    for (int jt0 = 0; jt0 < 32; jt0++) {
        int jt = jsplit * 32 + jt0;
        const float* sp = &ls1[jt * 32 + quad * 8];
        h8 ap;
        float ps = 0.f;
#pragma unroll
        for (int jj = 0; jj < 8; jj++) {
            float z = s2n + sp[jj];
            float p = __expf(leakyf_(z) - mi);
            ps += p;
            ap[jj] = (_Float16)p;
        }
        psum += ps;
#pragma unroll
        for (int hgi = 0; hgi < 4; hgi++) {
            int hg = whalf * 4 + hgi;
            h8 bb = *(const h8*)(hbsw + ((size_t)(jt * 8 + hg) * 64 + lane) * 8);
            acc[hgi] = __builtin_amdgcn_mfma_f32_16x16x32_f16(ap, bb, acc[hgi], 0, 0, 0);
        }
    }
    psum += __shfl_xor(psum, 16, 64);
    psum += __shfl_xor(psum, 32, 64);
    if (whalf == 0 && lane < 16) psr[jsplit][lane] = psum;
#pragma unroll
    for (int hgi = 0; hgi < 4; hgi++) {
        int h = (whalf * 4 + hgi) * 16 + m;
#pragma unroll
        for (int r = 0; r < 4; r++)
            red[jsplit][quad * 4 + r][h] = acc[hgi][r];
    }
    __syncthreads();
    if (tid < 16) {
        float pt = psr[0][tid] + psr[1][tid] + psr[2][tid] + psr[3][tid];
        psr[0][tid] = fastrcp_(pt);
    }
    __syncthreads();
#pragma unroll
    for (int cc = 0; cc < 4; cc++) {
        int c = cc * 512 + tid;
        int row = c >> 7, h = c & 127;
        float v = red[0][row][h] + red[1][row][h] + red[2][row][h] + red[3][row][h];
        h2s[row][h] = fmaf(v, psr[0][row], ws[HBN + (size_t)(n0 + row) * HH + h]);
    }
    __syncthreads();
    int row = tid >> 5, jj = tid & 31;
    float po = 0.f;
#pragma unroll
    for (int q = 0; q < 4; q++) {
        int j = q * 32 + jj;
        const float4* wr = (const float4*)(Wfc + (size_t)j * HH);
        float a = 0.f;
#pragma unroll 8
        for (int kq = 0; kq < 32; kq++) {
            float4 wv = wr[kq];
            float4 hv = *(const float4*)&h2s[row][kq * 4];
            a = fmaf(wv.x, hv.x, fmaf(wv.y, hv.y, fmaf(wv.z, hv.z, fmaf(wv.w, hv.w, a))));
        }
        po = fmaf(leakyf_(a + bfc[j]), Wout[j], po);
    }
#pragma unroll
    for (int o = 1; o < 32; o <<= 1) po += __shfl_xor(po, o, 64);
    if (jj == 0) out[n0 + row] = fastrcp_(1.f + __expf(-(po + bout[0])));
}

extern "C" void kernel_launch(void* const* d_in, const int* in_sizes, int n_in,
                              void* d_out, int out_size, void* d_ws, size_t ws_size,
                              hipStream_t stream) {
    const float* x = (const float*)d_in[0];
    const float* bn1_g = (const float*)d_in[1];
    const float* bn1_b = (const float*)d_in[2];
    const float* W_ih = (const float*)d_in[3];
    const float* W_hh = (const float*)d_in[4];
    const float* b_ih = (const float*)d_in[5];
    const float* b_hh = (const float*)d_in[6];
    const float* bn2_g = (const float*)d_in[7];
    const float* bn2_b = (const float*)d_in[8];
    const float* W_t = (const float*)d_in[9];
    const float* b_t = (const float*)d_in[10];
    const float* a = (const float*)d_in[11];
    const float* W_fc = (const float*)d_in[12];
    const float* b_fc = (const float*)d_in[13];
    const float* W_out = (const float*)d_in[14];
    const float* b_out = (const float*)d_in[15];
    float* ws = (float*)d_ws;
    float* out = (float*)d_out;

    k_pre<<<1409, 256, 0, stream>>>(x, W_ih, W_hh, W_t, b_t, a, ws);
    k_fin1<<<1, 1024, 0, stream>>>(bn1_g, bn1_b, W_ih, b_ih, b_hh, ws);
    k_lstmA<<<NN / 16, 512, 0, stream>>>(ws);
    k_lstmB<<<NN / 16, 512, 0, stream>>>(ws);
    k_hbn<<<NN / 32, 256, 0, stream>>>(bn2_g, bn2_b, ws);
    k_attfc<<<NN / 16, 512, 0, stream>>>(W_fc, b_fc, W_out, b_out, ws, out);
}

// Round 12
// 254.136 us; speedup vs baseline: 1.0325x; 1.0325x over previous
//
#include <hip/hip_runtime.h>
#include <math.h>

constexpr int NN = 4096, DD = 64, TT = 60, HH = 128, GG = 512, KK = 192;

typedef _Float16 h8 __attribute__((ext_vector_type(8)));
typedef float f4 __attribute__((ext_vector_type(4)));

// ws layout (float offsets)
constexpr size_t XNT = 0;                                  // half [T][N][D] RAW x fp16; REUSED later as swizzled hbn16
constexpr size_t WFRG = (size_t)TT * NN * DD / 2;          // half [w][g][ks][lane][8] = 98304 halves (UNfolded)
constexpr size_t BSUM = WFRG + 98304 / 2;                  // [512] f32 folded bias
constexpr size_t SC1 = BSUM + GG;                          // [64] (scratch)
constexpr size_t SH1 = SC1 + DD;                           // [64]
constexpr size_t HID = SH1 + DD;                           // [N][H] f32
constexpr size_t HBN = HID + (size_t)NN * HH;              // [N][H]
constexpr size_t SC2 = HBN + (size_t)NN * HH;              // [128] (unused now)
constexpr size_t SH2 = SC2 + HH;
constexpr size_t U1O = SH2 + HH;
constexpr size_t U2O = U1O + HH;
constexpr size_t CCO = U2O + HH;                           // [2]: c1, c2
constexpr size_t S1O = CCO + 4;                            // [N]
constexpr size_t S2O = S1O + NN;
constexpr size_t H2O = S2O + NN;                           // BN1 per-block partials [1024][128] (512 KB), else unused
constexpr size_t SSUM = H2O + (size_t)NN * HH;             // [132:260) bn2 sum, [260:388) bn2 sumsq (atomic accum)
constexpr size_t SC16 = SSUM + 392;                        // fp16[64] sc1 (32 floats)

// Fast activations: v_rcp_f32 (1 ulp) instead of correctly-rounded fp32 divide.
__device__ __forceinline__ float fastrcp_(float x) { return __builtin_amdgcn_rcpf(x); }
__device__ __forceinline__ float sigmoidf_(float x) { return fastrcp_(1.f + __expf(-x)); }
__device__ __forceinline__ float tanhfast_(float x) { return 1.f - 2.f * fastrcp_(__expf(2.f * x) + 1.f); }
__device__ __forceinline__ float leakyf_(float z) { return fmaxf(z, 0.01f * z); }

constexpr int TSTR = 264;  // halves per t-row in staging LDS

// ---- k_pre: blocks [0,1024) BN1 stats + fp16 transpose (partials to distinct
//      slots, NO done-counter); [1024,1408) weight swizzle; 1408 u/v/c prep. ----
__global__ __launch_bounds__(256) void k_pre(const float* __restrict__ x,
                                             const float* __restrict__ Wih,
                                             const float* __restrict__ Whh,
                                             const float* __restrict__ Wt,
                                             const float* __restrict__ bt,
                                             const float* __restrict__ a,
                                             float* __restrict__ ws) {
    int b = blockIdx.x;
    int tid = threadIdx.x;
    if (b >= 1024) {
        if (b == 1408) {
            int k = tid;
            if (k < HH) {
                float u1 = 0.f, u2 = 0.f;
                for (int j = 0; j < HH; j++) {
                    float w = Wt[j * HH + k];
                    u1 = fmaf(w, a[j], u1);
                    u2 = fmaf(w, a[HH + j], u2);
                }
                ws[U1O + k] = u1;
                ws[U2O + k] = u2;
                if (k == 0) {
                    float c1 = 0.f, c2 = 0.f;
                    for (int j = 0; j < HH; j++) {
                        c1 = fmaf(bt[j], a[j], c1);
                        c2 = fmaf(bt[j], a[HH + j], c2);
                    }
                    ws[CCO] = c1;
                    ws[CCO + 1] = c2;
                }
            }
            return;
        }
        // parallel weight swizzle (UNfolded): frag (w,g,ks): W[k][col],
        // col=g*128+w*16+(lane&15), k=ks*32+(lane>>4)*8+j
        int o = (b - 1024) * 256 + tid;
        _Float16* wf = (_Float16*)(ws + WFRG);
        int j = o & 7;
        int lane = (o >> 3) & 63;
        int rest = o >> 9;
        int ks = rest % 6;
        int gw = rest / 6;
        int g = gw & 3, w = gw >> 2;
        int col = g * 128 + w * 16 + (lane & 15);
        int k = ks * 32 + (lane >> 4) * 8 + j;
        float v = (k < DD) ? Wih[col * DD + k] : Whh[col * HH + (k - DD)];
        wf[o] = (_Float16)v;
        return;
    }
    // ---- xstats: rows n0..n0+3; coalesced reads; LDS [t][k] staging; b64 copy-out ----
    __shared__ _Float16 stg[TT * TSTR];
    __shared__ float rs[256], rss[256];
    const float4* xb = (const float4*)(x + (size_t)b * 15360);
#pragma unroll
    for (int q = 0; q < 15; q++) {
        int f = q * 256 + tid;
        float4 v = xb[f];
        int k = f / 15, t0 = (f - k * 15) * 4;
        stg[(t0 + 0) * TSTR + k] = (_Float16)v.x;
        stg[(t0 + 1) * TSTR + k] = (_Float16)v.y;
        stg[(t0 + 2) * TSTR + k] = (_Float16)v.z;
        stg[(t0 + 3) * TSTR + k] = (_Float16)v.w;
    }
    __syncthreads();
    {
        int k = tid;
        float s = 0.f, ss = 0.f;
#pragma unroll
        for (int t = 0; t < TT; t++) {
            float v = (float)stg[t * TSTR + k];
            s += v;
            ss = fmaf(v, v, ss);
        }
        rs[tid] = s; rss[tid] = ss;
    }
    __syncthreads();
    if (tid < 64) {
        float ts = rs[tid] + rs[64 + tid] + rs[128 + tid] + rs[192 + tid];
        float tss = rss[tid] + rss[64 + tid] + rss[128 + tid] + rss[192 + tid];
        float* pp = ws + H2O + (size_t)b * 128;
        pp[tid] = ts;
        pp[64 + tid] = tss;
    }
    // copy-out: xnT[t][n0..n0+3][0..63]
    _Float16* outp = (_Float16*)ws;
    int n0 = b * 4;
    for (int p = tid; p < 3840; p += 256) {
        int t = p >> 6, i = p & 63;
        *(uint2*)(outp + ((size_t)t * NN + n0) * DD + i * 4) =
            *(const uint2*)(stg + t * TSTR + i * 4);
    }
}

// ---- k_fin1: single block, 1024 threads. Zero BN2 accum; reduce 1024x128 BN1
//      partials; sc/sh; fp16 sc1; bias fold. ----
__global__ __launch_bounds__(1024) void k_fin1(const float* __restrict__ g1,
                                               const float* __restrict__ b1,
                                               const float* __restrict__ Wih,
                                               const float* __restrict__ bih,
                                               const float* __restrict__ bhh,
                                               float* __restrict__ ws) {
    __shared__ float p2[32][128];
    __shared__ float scs[64], shs[64];
    int tid = threadIdx.x;
    if (tid < 392) ws[SSUM + tid] = 0.f;
    {
        int rb = tid >> 5;
        int c0 = (tid & 31) * 4;
        const float* pb = ws + H2O + (size_t)rb * 32 * 128;
        float4 s4 = {0.f, 0.f, 0.f, 0.f};
        for (int bb = 0; bb < 32; bb++) {
            float4 v = *(const float4*)(pb + (size_t)bb * 128 + c0);
            s4.x += v.x; s4.y += v.y; s4.z += v.z; s4.w += v.w;
        }
        p2[rb][c0 + 0] = s4.x;
        p2[rb][c0 + 1] = s4.y;
        p2[rb][c0 + 2] = s4.z;
        p2[rb][c0 + 3] = s4.w;
    }
    __syncthreads();
    if (tid < 64) {
        float s_ = 0.f, ss_ = 0.f;
#pragma unroll
        for (int g = 0; g < 32; g++) {
            s_ += p2[g][tid];
            ss_ += p2[g][64 + tid];
        }
        float cnt = (float)(NN * TT);
        float m = s_ / cnt;
        float var = ss_ / cnt - m * m;
        float sc = g1[tid] * rsqrtf(var + 1e-5f);
        scs[tid] = sc;
        shs[tid] = b1[tid] - m * sc;
        ((_Float16*)(ws + SC16))[tid] = (_Float16)sc;
    }
    __syncthreads();
    if (tid < GG) {
        int c = tid;
        float bsum = bih[c] + bhh[c];
        const float4* wr = (const float4*)(Wih + c * 64);
#pragma unroll
        for (int q = 0; q < 16; q++) {
            float4 wv = wr[q];
            bsum = fmaf(wv.x, shs[q * 4 + 0], fmaf(wv.y, shs[q * 4 + 1],
                   fmaf(wv.z, shs[q * 4 + 2], fmaf(wv.w, shs[q * 4 + 3], bsum))));
        }
        ws[BSUM + c] = bsum;
    }
}

// ---- LSTM: MFMA, weights persistent in VGPRs; lgkmcnt-only in-loop barrier.
//      2x-unrolled t-loop with ping-pong xacc (xA/xB). (R10 proven form) ----
__global__ __launch_bounds__(512, 1) void k_lstm(float* __restrict__ ws) {
    int tid = threadIdx.x;
    int w = tid >> 6, lane = tid & 63;
    int quad = lane >> 4, m = lane & 15;
    int r0 = blockIdx.x * 16;
    __shared__ _Float16 hlds[2][16][136];
    const _Float16* wf = (const _Float16*)(ws + WFRG);

    h8 bw[4][6];
#pragma unroll
    for (int g = 0; g < 4; g++)
#pragma unroll
        for (int ks = 0; ks < 6; ks++)
            bw[g][ks] = *(const h8*)(wf + ((((w * 4 + g) * 6 + ks) * 64 + lane) * 8));

    f4 xbias[4];
#pragma unroll
    for (int g = 0; g < 4; g++) {
        float bv = ws[BSUM + g * 128 + w * 16 + m];
        xbias[g] = (f4){bv, bv, bv, bv};
    }

    const _Float16* sc16 = (const _Float16*)(ws + SC16);
    {
        h8 scv0 = *(const h8*)(sc16 + quad * 8);
        h8 scv1 = *(const h8*)(sc16 + 32 + quad * 8);
        // register-side sc1 fold: W·diag(sc)·x == W·(sc⊙x)
#pragma unroll
        for (int g = 0; g < 4; g++) { bw[g][0] *= scv0; bw[g][1] *= scv1; }
    }

    for (int p = tid; p < 2 * 16 * 136; p += 512) ((_Float16*)hlds)[p] = (_Float16)0.f;

    f4 cst = {};
    float hv[4];
    const _Float16* xb = (const _Float16*)ws + (size_t)(r0 + m) * DD + quad * 8;
    int col = w * 16 + m;
    __syncthreads();

    // prologue: xA = bias + x_0·Wx (bias enters as MFMA C-input)
    h8 ax0 = *(const h8*)xb;
    h8 ax1 = *(const h8*)(xb + 32);
    f4 xA[4], xB[4];
#pragma unroll
    for (int g = 0; g < 4; g++) xA[g] = __builtin_amdgcn_mfma_f32_16x16x32_f16(ax0, bw[g][0], xbias[g], 0, 0, 0);
#pragma unroll
    for (int g = 0; g < 4; g++) xA[g] = __builtin_amdgcn_mfma_f32_16x16x32_f16(ax1, bw[g][1], xA[g], 0, 0, 0);

    for (int t = 0; t < TT; t += 2) {
        // ---- even step: consume xA (in place), build xB for t+1 ----
        {
            h8 ah[4];
            const _Float16* hb = &hlds[1][m][quad * 8];
#pragma unroll
            for (int ks = 0; ks < 4; ks++) ah[ks] = *(const h8*)(hb + ks * 32);
            // t even <= 58, so t+1 <= 59 always valid
            const _Float16* xp = xb + (size_t)(t + 1) * NN * DD;
            h8 nx0 = *(const h8*)xp;
            h8 nx1 = *(const h8*)(xp + 32);
#pragma unroll
            for (int ks = 0; ks < 4; ks++)
#pragma unroll
                for (int g = 0; g < 4; g++)
                    xA[g] = __builtin_amdgcn_mfma_f32_16x16x32_f16(ah[ks], bw[g][ks + 2], xA[g], 0, 0, 0);
#pragma unroll
            for (int r = 0; r < 4; r++) {
                float ig = sigmoidf_(xA[0][r]);
                float fg = sigmoidf_(xA[1][r]);
                float gg = tanhfast_(xA[2][r]);
                float og = sigmoidf_(xA[3][r]);
                float c = fmaf(fg, cst[r], ig * gg);
                cst[r] = c;
                hv[r] = og * tanhfast_(c);
            }
            _Float16* wbuf = &hlds[0][0][0];
#pragma unroll
            for (int r = 0; r < 4; r++) wbuf[(quad * 4 + r) * 136 + col] = (_Float16)hv[r];
#pragma unroll
            for (int g = 0; g < 4; g++) xB[g] = __builtin_amdgcn_mfma_f32_16x16x32_f16(nx0, bw[g][0], xbias[g], 0, 0, 0);
#pragma unroll
            for (int g = 0; g < 4; g++) xB[g] = __builtin_amdgcn_mfma_f32_16x16x32_f16(nx1, bw[g][1], xB[g], 0, 0, 0);
            asm volatile("s_waitcnt lgkmcnt(0)\n\ts_barrier" ::: "memory");
        }
        // ---- odd step: consume xB (in place), build xA for t+2 ----
        {
            h8 ah[4];
            const _Float16* hb = &hlds[0][m][quad * 8];
#pragma unroll
            for (int ks = 0; ks < 4; ks++) ah[ks] = *(const h8*)(hb + ks * 32);
            h8 nx0 = {}, nx1 = {};
            if (t + 2 < TT) {
                const _Float16* xp = xb + (size_t)(t + 2) * NN * DD;
                nx0 = *(const h8*)xp;
                nx1 = *(const h8*)(xp + 32);
            }
#pragma unroll
            for (int ks = 0; ks < 4; ks++)
#pragma unroll
                for (int g = 0; g < 4; g++)
                    xB[g] = __builtin_amdgcn_mfma_f32_16x16x32_f16(ah[ks], bw[g][ks + 2], xB[g], 0, 0, 0);
#pragma unroll
            for (int r = 0; r < 4; r++) {
                float ig = sigmoidf_(xB[0][r]);
                float fg = sigmoidf_(xB[1][r]);
                float gg = tanhfast_(xB[2][r]);
                float og = sigmoidf_(xB[3][r]);
                float c = fmaf(fg, cst[r], ig * gg);
                cst[r] = c;
                hv[r] = og * tanhfast_(c);
            }
            _Float16* wbuf = &hlds[1][0][0];
#pragma unroll
            for (int r = 0; r < 4; r++) wbuf[(quad * 4 + r) * 136 + col] = (_Float16)hv[r];
#pragma unroll
            for (int g = 0; g < 4; g++) xA[g] = __builtin_amdgcn_mfma_f32_16x16x32_f16(nx0, bw[g][0], xbias[g], 0, 0, 0);
#pragma unroll
            for (int g = 0; g < 4; g++) xA[g] = __builtin_amdgcn_mfma_f32_16x16x32_f16(nx1, bw[g][1], xA[g], 0, 0, 0);
            asm volatile("s_waitcnt lgkmcnt(0)\n\ts_barrier" ::: "memory");
        }
    }
#pragma unroll
    for (int r = 0; r < 4; r++)
        ws[HID + (size_t)(r0 + quad * 4 + r) * HH + col] = hv[r];

    // BN2 partial sums (wave-local reduce; 1 atomic/col to 256 distinct addrs)
    float s = hv[0] + hv[1] + hv[2] + hv[3];
    float ss = fmaf(hv[0], hv[0], fmaf(hv[1], hv[1], fmaf(hv[2], hv[2], hv[3] * hv[3])));
    s += __shfl_xor(s, 16, 64); s += __shfl_xor(s, 32, 64);
    ss += __shfl_xor(ss, 16, 64); ss += __shfl_xor(ss, 32, 64);
    if (quad == 0) {
        atomicAdd(&ws[SSUM + 132 + col], s);
        atomicAdd(&ws[SSUM + 260 + col], ss);
    }
}

// ---- apply BN2 (sc/sh computed in-block from SSUM): s1, s2, fp32 hbn,
//      LDS-staged coalesced swizzled fp16 hbn. NO global s1max atomic —
//      the 4096-deep single-address atomicMax chain (one per row) was a
//      serialized RMW chain like R5's done-counter; s1max is now computed
//      block-locally in k_attfc from its full ls1 copy (identical value). ----
__global__ void k_hbn(const float* __restrict__ g2,
                      const float* __restrict__ b2,
                      float* __restrict__ ws) {
    __shared__ float sc[HH], sh[HH], u1s[HH], u2s[HH];
    __shared__ _Float16 swz[4096];
    int tid = threadIdx.x;
    if (tid < HH) {
        float mm = ws[SSUM + 132 + tid] * (1.f / (float)NN);
        float var = ws[SSUM + 260 + tid] * (1.f / (float)NN) - mm * mm;
        float scv = g2[tid] * rsqrtf(var + 1e-5f);
        sc[tid] = scv;
        sh[tid] = b2[tid] - mm * scv;
        u1s[tid] = ws[U1O + tid]; u2s[tid] = ws[U2O + tid];
    }
    __syncthreads();
    int r = tid >> 3, l = tid & 7;
    int n = blockIdx.x * 32 + r;
    const float* hr = ws + HID + (size_t)n * HH;
    float* hb = ws + HBN + (size_t)n * HH;
    int lanehi = (r >> 3);
    int jj = r & 7;
    float d1 = 0.f, d2 = 0.f;
    int k0 = l * 16;
#pragma unroll
    for (int q4 = 0; q4 < 4; q4++) {
        float4 hv4 = *(const float4*)&hr[k0 + q4 * 4];
        float4 o;
#pragma unroll
        for (int c = 0; c < 4; c++) {
            int kk = k0 + q4 * 4 + c;
            float v = fmaf(((const float*)&hv4)[c], sc[kk], sh[kk]);
            ((float*)&o)[c] = v;
            swz[l * 512 + (lanehi * 16 + (kk & 15)) * 8 + jj] = (_Float16)v;
            d1 = fmaf(v, u1s[kk], d1);
            d2 = fmaf(v, u2s[kk], d2);
        }
        *(float4*)&hb[k0 + q4 * 4] = o;
    }
#pragma unroll
    for (int o = 1; o < 8; o <<= 1) { d1 += __shfl_xor(d1, o, 64); d2 += __shfl_xor(d2, o, 64); }
    if (l == 0) {
        ws[S1O + n] = d1 + ws[CCO];
        ws[S2O + n] = d2 + ws[CCO + 1];
    }
    __syncthreads();
    _Float16* dst = (_Float16*)ws + (size_t)blockIdx.x * 4096;
    for (int p = tid; p < 512; p += 256)
        *(h8*)(dst + p * 8) = *(const h8*)(swz + p * 8);
}

// ---- attention + fc fused; waves split the j-range (exp dedup).
//      s1max computed block-locally during the ls1 load (identical to the
//      old global atomicMax value — every block holds all 4096 s1). ----
__global__ __launch_bounds__(512, 1) void k_attfc(const float* __restrict__ Wfc,
                                                  const float* __restrict__ bfc,
                                                  const float* __restrict__ Wout,
                                                  const float* __restrict__ bout,
                                                  float* __restrict__ ws,
                                                  float* __restrict__ out) {
    __shared__ float ls1[NN];
    __shared__ float red[4][16][132];
    __shared__ float psr[4][16];
    __shared__ float h2s[16][132];
    __shared__ float wmax[8];
    int tid = threadIdx.x;
    int w = tid >> 6, lane = tid & 63;
    int quad = lane >> 4, m = lane & 15;
    int whalf = w >> 2, jsplit = w & 3;
    int n0 = blockIdx.x * 16;
    float lm = -1e30f;
    for (int i = tid; i < NN; i += 512) {
        float v = ws[S1O + i];
        ls1[i] = v;
        lm = fmaxf(lm, v);
    }
#pragma unroll
    for (int o = 1; o < 64; o <<= 1) lm = fmaxf(lm, __shfl_xor(lm, o, 64));
    if (lane == 0) wmax[w] = lm;
    __syncthreads();
    float s1max = wmax[0];
#pragma unroll
    for (int q = 1; q < 8; q++) s1max = fmaxf(s1max, wmax[q]);
    float s2n = ws[S2O + n0 + m];
    float mi = leakyf_(s2n + s1max);
    const _Float16* hbsw = (const _Float16*)ws;
    f4 acc[4] = {};
    float psum = 0.f;
    for (int jt0 = 0; jt0 < 32; jt0++) {
        int jt = jsplit * 32 + jt0;
        const float* sp = &ls1[jt * 32 + quad * 8];
        h8 ap;
        float ps = 0.f;
#pragma unroll
        for (int jj = 0; jj < 8; jj++) {
            float z = s2n + sp[jj];
            float p = __expf(leakyf_(z) - mi);
            ps += p;
            ap[jj] = (_Float16)p;
        }
        psum += ps;
#pragma unroll
        for (int hgi = 0; hgi < 4; hgi++) {
            int hg = whalf * 4 + hgi;
            h8 bb = *(const h8*)(hbsw + ((size_t)(jt * 8 + hg) * 64 + lane) * 8);
            acc[hgi] = __builtin_amdgcn_mfma_f32_16x16x32_f16(ap, bb, acc[hgi], 0, 0, 0);
        }
    }
    psum += __shfl_xor(psum, 16, 64);
    psum += __shfl_xor(psum, 32, 64);
    if (whalf == 0 && lane < 16) psr[jsplit][lane] = psum;
#pragma unroll
    for (int hgi = 0; hgi < 4; hgi++) {
        int h = (whalf * 4 + hgi) * 16 + m;
#pragma unroll
        for (int r = 0; r < 4; r++)
            red[jsplit][quad * 4 + r][h] = acc[hgi][r];
    }
    __syncthreads();
    if (tid < 16) {
        float pt = psr[0][tid] + psr[1][tid] + psr[2][tid] + psr[3][tid];
        psr[0][tid] = fastrcp_(pt);
    }
    __syncthreads();
#pragma unroll
    for (int cc = 0; cc < 4; cc++) {
        int c = cc * 512 + tid;
        int row = c >> 7, h = c & 127;
        float v = red[0][row][h] + red[1][row][h] + red[2][row][h] + red[3][row][h];
        h2s[row][h] = fmaf(v, psr[0][row], ws[HBN + (size_t)(n0 + row) * HH + h]);
    }
    __syncthreads();
    int row = tid >> 5, jj = tid & 31;
    float po = 0.f;
#pragma unroll
    for (int q = 0; q < 4; q++) {
        int j = q * 32 + jj;
        const float4* wr = (const float4*)(Wfc + (size_t)j * HH);
        float a = 0.f;
#pragma unroll 8
        for (int kq = 0; kq < 32; kq++) {
            float4 wv = wr[kq];
            float4 hv = *(const float4*)&h2s[row][kq * 4];
            a = fmaf(wv.x, hv.x, fmaf(wv.y, hv.y, fmaf(wv.z, hv.z, fmaf(wv.w, hv.w, a))));
        }
        po = fmaf(leakyf_(a + bfc[j]), Wout[j], po);
    }
#pragma unroll
    for (int o = 1; o < 32; o <<= 1) po += __shfl_xor(po, o, 64);
    if (jj == 0) out[n0 + row] = fastrcp_(1.f + __expf(-(po + bout[0])));
}

extern "C" void kernel_launch(void* const* d_in, const int* in_sizes, int n_in,
                              void* d_out, int out_size, void* d_ws, size_t ws_size,
                              hipStream_t stream) {
    const float* x = (const float*)d_in[0];
    const float* bn1_g = (const float*)d_in[1];
    const float* bn1_b = (const float*)d_in[2];
    const float* W_ih = (const float*)d_in[3];
    const float* W_hh = (const float*)d_in[4];
    const float* b_ih = (const float*)d_in[5];
    const float* b_hh = (const float*)d_in[6];
    const float* bn2_g = (const float*)d_in[7];
    const float* bn2_b = (const float*)d_in[8];
    const float* W_t = (const float*)d_in[9];
    const float* b_t = (const float*)d_in[10];
    const float* a = (const float*)d_in[11];
    const float* W_fc = (const float*)d_in[12];
    const float* b_fc = (const float*)d_in[13];
    const float* W_out = (const float*)d_in[14];
    const float* b_out = (const float*)d_in[15];
    float* ws = (float*)d_ws;
    float* out = (float*)d_out;

    k_pre<<<1409, 256, 0, stream>>>(x, W_ih, W_hh, W_t, b_t, a, ws);
    k_fin1<<<1, 1024, 0, stream>>>(bn1_g, bn1_b, W_ih, b_ih, b_hh, ws);
    k_lstm<<<NN / 16, 512, 0, stream>>>(ws);
    k_hbn<<<NN / 32, 256, 0, stream>>>(bn2_g, bn2_b, ws);
    k_attfc<<<NN / 16, 512, 0, stream>>>(W_fc, b_fc, W_out, b_out, ws, out);
}